// Round 12
// baseline (59.555 us; speedup 1.0000x reference)
//
#include <hip/hip_runtime.h>
#include <hip/hip_fp16.h>
#include <cfloat>
#include <math.h>

namespace {
constexpr int   B      = 4;
constexpr int   N      = 8192;
constexpr int   KNN    = 16;
constexpr float EPSV   = 1e-12f;

// --- main (fp16) kernel geometry: 4-wave blocks, 8 rows/wave ---
constexpr int   THREADS = 256;            // 4 waves
constexpr int   WAVES   = THREADS / 64;   // 4
constexpr int   RPW     = 8;              // query rows per wave == 8 eighths
constexpr int   RPB     = WAVES * RPW;    // 32 rows per block
constexpr int   BPB     = N / RPB;        // 256 blocks per batch
constexpr int   GRID    = B * BPB;        // 1024 blocks = 4096 waves
constexpr int   GROUPS  = N / 256;        // 32 groups of 256 candidates

// --- fallback (LDS) geometry (R5 kernel, proven) ---
constexpr int   THREADS2 = 512;
constexpr int   WAVES2   = THREADS2 / 64;
constexpr int   RPW2     = 8;
constexpr int   RPB2     = WAVES2 * RPW2; // 64
constexpr int   BPB2     = N / RPB2;      // 128
constexpr int   GRID2    = B * BPB2;      // 512
constexpr int   TILE2    = 1024;
constexpr int   NTILES2  = N / TILE2;

constexpr size_t PH_BYTES = (size_t)B * N * sizeof(uint2);   // 256 KB
}

__device__ __forceinline__ float rfl(float x) {
    return __int_as_float(__builtin_amdgcn_readfirstlane(__float_as_int(x)));
}

__device__ __forceinline__ float fast_sqrt(float x) {
#if defined(__has_builtin) && __has_builtin(__builtin_amdgcn_sqrtf)
    return __builtin_amdgcn_sqrtf(x);
#else
    return sqrtf(x);
#endif
}

// ---------- prepass: quantize cloud to fp16, pack (x,y) | (z,0) in 8B ----------
__global__ __launch_bounds__(256)
void knn_prep16(const float* __restrict__ pc, uint2* __restrict__ ph)
{
    const int i = blockIdx.x * 256 + threadIdx.x;
    if (i < B * N) {
        const __half hx = __float2half(pc[3 * i + 0]);
        const __half hy = __float2half(pc[3 * i + 1]);
        const __half hz = __float2half(pc[3 * i + 2]);
        uint2 o;
        o.x = ((unsigned)__half_as_ushort(hy) << 16) | (unsigned)__half_as_ushort(hx);
        o.y = (unsigned)__half_as_ushort(hz);
        ph[i] = o;
    }
}

// unpack 8B candidate -> f32 (x, y, z, |c|^2); all math in f32 on quantized values
__device__ __forceinline__ void unpack_cand(const uint2 a, float& cx, float& cy, float& cz, float& cs)
{
    const __half2 hxy = *reinterpret_cast<const __half2*>(&a.x);
    const float2  f   = __half22float2(hxy);
    cx = f.x; cy = f.y;
    cz = __half2float(__ushort_as_half((unsigned short)(a.y & 0xffffu)));
    cs = fmaf(cz, cz, fmaf(cy, cy, cx * cx));
}

// ---------- per-lane sorted top-4-of-8 ----------
__device__ __forceinline__ void top4_of_8(const float m[8], float L[4])
{
    const float a0 = fminf(m[0], m[1]), b0 = fmaxf(m[0], m[1]);
    const float a1 = fminf(m[2], m[3]), b1 = fmaxf(m[2], m[3]);
    const float a2 = fminf(m[4], m[5]), b2 = fmaxf(m[4], m[5]);
    const float a3 = fminf(m[6], m[7]), b3 = fmaxf(m[6], m[7]);
    const float p0 = fminf(a0, a1), xP = fmaxf(a0, a1), yP = fminf(b0, b1), p3 = fmaxf(b0, b1);
    const float p1 = fminf(xP, yP), p2 = fmaxf(xP, yP);
    const float q0 = fminf(a2, a3), xQ = fmaxf(a2, a3), yQ = fminf(b2, b3), q3 = fmaxf(b2, b3);
    const float q1 = fminf(xQ, yQ), q2 = fmaxf(xQ, yQ);
    const float l0 = fminf(p0, q3), l1 = fminf(p1, q2), l2 = fminf(p2, q1), l3 = fminf(p3, q0);
    const float t0 = fminf(l0, l2), t2 = fmaxf(l0, l2);
    const float t1 = fminf(l1, l3), t3 = fmaxf(l1, l3);
    L[0] = fminf(t0, t1); L[1] = fmaxf(t0, t1);
    L[2] = fminf(t2, t3); L[3] = fmaxf(t2, t3);
}

// ---------- keep-4 merge of two ascending sorted-4 lists (exact tournament) ----------
__device__ __forceinline__ float4 merge44(const float4 a, const float4 b)
{
    const float l0 = fminf(a.x, b.w), l1 = fminf(a.y, b.z);
    const float l2 = fminf(a.z, b.y), l3 = fminf(a.w, b.x);
    const float t0 = fminf(l0, l2), t2 = fmaxf(l0, l2);
    const float t1 = fminf(l1, l3), t3 = fmaxf(l1, l3);
    return make_float4(fminf(t0, t1), fmaxf(t0, t1), fminf(t2, t3), fmaxf(t2, t3));
}

// ---------- legacy merge (fallback kernel only) ----------
template <int NROWS>
__device__ __forceinline__ float merge_and_sum(float L[NROWS][4], const float* qs)
{
#pragma unroll
    for (int r = 0; r < NROWS; ++r) {
        const float p0 = __shfl_xor(L[r][0], 1, 64);
        const float p1 = __shfl_xor(L[r][1], 1, 64);
        const float p2 = __shfl_xor(L[r][2], 1, 64);
        const float p3 = __shfl_xor(L[r][3], 1, 64);
        const float l0 = fminf(L[r][0], p3), l1 = fminf(L[r][1], p2);
        const float l2 = fminf(L[r][2], p1), l3 = fminf(L[r][3], p0);
        const float t0 = fminf(l0, l2), t2 = fmaxf(l0, l2);
        const float t1 = fminf(l1, l3), t3 = fmaxf(l1, l3);
        L[r][0] = fminf(t0, t1); L[r][1] = fmaxf(t0, t1);
        L[r][2] = fminf(t2, t3); L[r][3] = fmaxf(t2, t3);
    }
    float racc[NROWS];
#pragma unroll
    for (int r = 0; r < NROWS; ++r) racc[r] = 0.0f;
#pragma unroll
    for (int k = 0; k < KNN; ++k) {
#pragma unroll
        for (int r = 0; r < NROWS; ++r) {
            float m = L[r][0];
            m = fminf(m, __shfl_xor(m, 2, 64));
            m = fminf(m, __shfl_xor(m, 4, 64));
            m = fminf(m, __shfl_xor(m, 8, 64));
            m = fminf(m, __shfl_xor(m, 16, 64));
            m = fminf(m, __shfl_xor(m, 32, 64));
            racc[r] += fast_sqrt(fmaxf(qs[r] + m, 0.0f) + EPSV);
            const bool take = (L[r][0] == m);
            L[r][0] = take ? L[r][1] : L[r][0];
            L[r][1] = take ? L[r][2] : L[r][1];
            L[r][2] = take ? L[r][3] : L[r][2];
            L[r][3] = take ? FLT_MAX : L[r][3];
        }
    }
    float wsum = 0.0f;
#pragma unroll
    for (int r = 0; r < NROWS; ++r) wsum += racc[r];
    return wsum;
}

// ---------- main kernel: fp16 candidates, 8 rows/wave, eighth-merge ----------
__global__ __launch_bounds__(THREADS)
__attribute__((amdgpu_waves_per_eu(2, 4)))   // cap 256 VGPR (R5/R8-proven honored) — no spill
void knn_tv_f16(const uint2* __restrict__ hp, float* __restrict__ outbuf)
{
    __shared__ float4 sMerge[WAVES][RPW][64];   // 32 KB
    __shared__ float  sWaveSum[WAVES];

    const int tid   = threadIdx.x;
    const int lane  = tid & 63;
    const int wave  = tid >> 6;
    const int blk   = blockIdx.x;
    const int batch = blk / BPB;
    const int row0  = (blk % BPB) * RPB + wave * RPW;

    const uint2* __restrict__ hb = hp + (size_t)batch * (size_t)N;

    // queries from the SAME quantized values (self-distance exactly 0); SGPR via rfl
    float qx[RPW], qy[RPW], qz[RPW], qs[RPW];
#pragma unroll
    for (int r = 0; r < RPW; ++r) {
        float fx, fy, fz, fs;
        unpack_cand(hb[row0 + r], fx, fy, fz, fs);
        qx[r] = rfl(-2.0f * fx);
        qy[r] = rfl(-2.0f * fy);
        qz[r] = rfl(-2.0f * fz);
        qs[r] = rfl(fs);
    }

    // per-(lane, slot) stream minima of v = |c|^2 - 2 q.c  (8 slots/lane = 512 streams/row)
    float m0[RPW][8];
#pragma unroll
    for (int r = 0; r < RPW; ++r)
#pragma unroll
        for (int j = 0; j < 8; ++j)
            m0[r][j] = FLT_MAX;

    // 32 groups of 256 candidates; slot-pair index q is COMPILE-TIME (rule #20);
    // min3 folds two candidates per slot; unroll 2 for load pipelining (R9-proven).
    const uint2* __restrict__ p = hb + lane;
#pragma unroll 2
    for (int gg = 0; gg < GROUPS / 4; ++gg) {
#pragma unroll
        for (int q = 0; q < 4; ++q) {
            const int off = (gg * 4 + q) * 256;
            const uint2 a0 = p[off +   0];
            const uint2 a1 = p[off +  64];
            const uint2 a2 = p[off + 128];
            const uint2 a3 = p[off + 192];
            float cx0, cy0, cz0, cs0;  unpack_cand(a0, cx0, cy0, cz0, cs0);
            float cx1, cy1, cz1, cs1;  unpack_cand(a1, cx1, cy1, cz1, cs1);
            float cx2, cy2, cz2, cs2;  unpack_cand(a2, cx2, cy2, cz2, cs2);
            float cx3, cy3, cz3, cs3;  unpack_cand(a3, cx3, cy3, cz3, cs3);
#pragma unroll
            for (int r = 0; r < RPW; ++r) {
                const float v0 = fmaf(cx0, qx[r], fmaf(cy0, qy[r], fmaf(cz0, qz[r], cs0)));
                const float v1 = fmaf(cx1, qx[r], fmaf(cy1, qy[r], fmaf(cz1, qz[r], cs1)));
                const float v2 = fmaf(cx2, qx[r], fmaf(cy2, qy[r], fmaf(cz2, qz[r], cs2)));
                const float v3 = fmaf(cx3, qx[r], fmaf(cy3, qy[r], fmaf(cz3, qz[r], cs3)));
                m0[r][2 * q + 0] = fminf(m0[r][2 * q + 0], fminf(v0, v1));   // v_min3_f32
                m0[r][2 * q + 1] = fminf(m0[r][2 * q + 1], fminf(v2, v3));   // v_min3_f32
            }
        }
    }

    // stash per-lane sorted top-4 per row
#pragma unroll
    for (int r = 0; r < RPW; ++r) {
        float L4[4];
        top4_of_8(m0[r], L4);
        sMerge[wave][r][lane] = make_float4(L4[0], L4[1], L4[2], L4[3]);
    }
    __syncthreads();

    // eighth e (8 lanes) owns row e: gather 8 lists -> exact top-4-of-32, then
    // 16 pops with 3-step butterflies (one pop loop serves all 8 rows).
    const int e = lane >> 3;
    const int j = lane & 7;
    float4 g[8];
#pragma unroll
    for (int t = 0; t < 8; ++t) g[t] = sMerge[wave][e][j + 8 * t];
    const float4 G = merge44(merge44(merge44(g[0], g[1]), merge44(g[2], g[3])),
                             merge44(merge44(g[4], g[5]), merge44(g[6], g[7])));

    // qs[e] via static-index lane-bit mux (rule #20)
    const float qsa = (lane & 8) ? qs[1] : qs[0];
    const float qsb = (lane & 8) ? qs[3] : qs[2];
    const float qsc = (lane & 8) ? qs[5] : qs[4];
    const float qsd = (lane & 8) ? qs[7] : qs[6];
    const float qse = (lane & 16) ? qsb : qsa;
    const float qsf = (lane & 16) ? qsd : qsc;
    const float qsq = (lane & 32) ? qsf : qse;

    float G0 = G.x, G1 = G.y, G2 = G.z, G3 = G.w;
    float rsum = 0.0f;
#pragma unroll
    for (int k = 0; k < KNN; ++k) {
        float m = G0;
        m = fminf(m, __shfl_xor(m, 1, 64));
        m = fminf(m, __shfl_xor(m, 2, 64));
        m = fminf(m, __shfl_xor(m, 4, 64));
        rsum += fast_sqrt(fmaxf(qsq + m, 0.0f) + EPSV);
        const bool take = (G0 == m);
        G0 = take ? G1 : G0;
        G1 = take ? G2 : G1;
        G2 = take ? G3 : G2;
        G3 = take ? FLT_MAX : G3;
    }

    // combine rows: xor 8/16/32 sums across the 8 eighths (j untouched)
    float tot = rsum + __shfl_xor(rsum, 8, 64);
    tot += __shfl_xor(tot, 16, 64);
    tot += __shfl_xor(tot, 32, 64);

    if (lane == 0) sWaveSum[wave] = tot;
    __syncthreads();
    if (tid == 0) {
        float t = 0.0f;
#pragma unroll
        for (int w = 0; w < WAVES; ++w) t += sWaveSum[w];
        outbuf[blk] = t;
    }
}

// ---------- fallback: R5's LDS-staged fp32 kernel (proven, unchanged) ----------
template <int ATOMIC>
__global__ __launch_bounds__(THREADS2)
__attribute__((amdgpu_waves_per_eu(2, 4)))
void knn_tv_lds(const float* __restrict__ pc, float* __restrict__ outbuf)
{
    __shared__ float sX[TILE2], sY[TILE2], sZ[TILE2], sS[TILE2];
    __shared__ float sWaveSum[WAVES2];

    const int tid   = threadIdx.x;
    const int lane  = tid & 63;
    const int wave  = tid >> 6;
    const int blk   = blockIdx.x;
    const int batch = blk / BPB2;
    const int row0  = (blk % BPB2) * RPB2 + wave * RPW2;

    const float* __restrict__ base = pc + (size_t)batch * (size_t)N * 3;

    float qx[RPW2], qy[RPW2], qz[RPW2], qs[RPW2];
#pragma unroll
    for (int r = 0; r < RPW2; ++r) {
        const int row = row0 + r;
        const float x = base[row * 3 + 0];
        const float y = base[row * 3 + 1];
        const float z = base[row * 3 + 2];
        qx[r] = rfl(-2.0f * x); qy[r] = rfl(-2.0f * y); qz[r] = rfl(-2.0f * z);
        qs[r] = rfl(fmaf(z, z, fmaf(y, y, x * x)));
    }

    float m0[RPW2][8];
#pragma unroll
    for (int r = 0; r < RPW2; ++r)
#pragma unroll
        for (int c = 0; c < 8; ++c) m0[r][c] = FLT_MAX;

    for (int tile = 0; tile < NTILES2; ++tile) {
        __syncthreads();
#pragma unroll
        for (int h = 0; h < 2; ++h) {
            const int p  = tid + h * THREADS2;
            const int gp = tile * TILE2 + p;
            const float x = base[gp * 3 + 0];
            const float y = base[gp * 3 + 1];
            const float z = base[gp * 3 + 2];
            sX[p] = x; sY[p] = y; sZ[p] = z;
            sS[p] = fmaf(z, z, fmaf(y, y, x * x));
        }
        __syncthreads();

#pragma unroll
        for (int grp = 0; grp < 4; ++grp) {
            const int o = grp * 256 + 4 * lane;
            const float4 CX = *(const float4*)&sX[o];
            const float4 CY = *(const float4*)&sY[o];
            const float4 CZ = *(const float4*)&sZ[o];
            const float4 CS = *(const float4*)&sS[o];
            const float cx[4] = {CX.x, CX.y, CX.z, CX.w};
            const float cy[4] = {CY.x, CY.y, CY.z, CY.w};
            const float cz[4] = {CZ.x, CZ.y, CZ.z, CZ.w};
            const float cs[4] = {CS.x, CS.y, CS.z, CS.w};
            const int jb = (grp & 1) * 4;
#pragma unroll
            for (int r = 0; r < RPW2; ++r)
#pragma unroll
                for (int i = 0; i < 4; ++i) {
                    const float v = fmaf(cx[i], qx[r], fmaf(cy[i], qy[r], fmaf(cz[i], qz[r], cs[i])));
                    m0[r][jb + i] = fminf(m0[r][jb + i], v);
                }
        }
    }

    float L[RPW2][4];
#pragma unroll
    for (int r = 0; r < RPW2; ++r) top4_of_8(m0[r], L[r]);

    const float wsum = merge_and_sum<RPW2>(L, qs);

    if (lane == 0) sWaveSum[wave] = wsum;
    __syncthreads();
    if (tid == 0) {
        float t = 0.0f;
#pragma unroll
        for (int w = 0; w < WAVES2; ++w) t += sWaveSum[w];
        if (ATOMIC) atomicAdd(outbuf, t * (1.0f / (float)(B * N)));
        else        outbuf[blk] = t;
    }
}

__global__ __launch_bounds__(256)
void knn_tv_reduce(const float* __restrict__ partial, float* __restrict__ out, int n)
{
    __shared__ float s[4];
    const int tid = threadIdx.x;
    float v = 0.0f;
    for (int i = tid; i < n; i += 256) v += partial[i];
#pragma unroll
    for (int off = 1; off < 64; off <<= 1) v += __shfl_xor(v, off, 64);
    if ((tid & 63) == 0) s[tid >> 6] = v;
    __syncthreads();
    if (tid == 0) {
        const float t = s[0] + s[1] + s[2] + s[3];
        out[0] = t * (1.0f / (float)(B * N));
    }
}

extern "C" void kernel_launch(void* const* d_in, const int* in_sizes, int n_in,
                              void* d_out, int out_size, void* d_ws, size_t ws_size,
                              hipStream_t stream)
{
    const float* pc  = (const float*)d_in[0];
    float*       out = (float*)d_out;

    if (ws_size >= PH_BYTES + GRID * sizeof(float)) {
        uint2* ph      = (uint2*)d_ws;
        float* partial = (float*)((char*)d_ws + PH_BYTES);
        knn_prep16<<<(B * N + 255) / 256, 256, 0, stream>>>(pc, ph);
        knn_tv_f16<<<GRID, THREADS, 0, stream>>>(ph, partial);
        knn_tv_reduce<<<1, 256, 0, stream>>>(partial, out, GRID);
    } else if (ws_size >= GRID2 * sizeof(float)) {
        float* partial = (float*)d_ws;
        knn_tv_lds<0><<<GRID2, THREADS2, 0, stream>>>(pc, partial);
        knn_tv_reduce<<<1, 256, 0, stream>>>(partial, out, GRID2);
    } else {
        hipMemsetAsync(d_out, 0, sizeof(float), stream);
        knn_tv_lds<1><<<GRID2, THREADS2, 0, stream>>>(pc, out);
    }
}

// Round 13
// 54.332 us; speedup vs baseline: 1.0961x; 1.0961x over previous
//
#include <hip/hip_runtime.h>
#include <cfloat>
#include <math.h>

namespace {
constexpr int   B      = 4;
constexpr int   N      = 8192;
constexpr int   KNN    = 16;
constexpr float EPSV   = 1e-12f;

// --- main kernel geometry (R10-proven): 4-wave blocks, 4 rows/wave ---
constexpr int   THREADS = 256;            // 4 waves
constexpr int   WAVES   = THREADS / 64;   // 4
constexpr int   RPW     = 4;              // query rows per wave == 4 quarters
constexpr int   RPB     = WAVES * RPW;    // 16 rows per block
constexpr int   BPB     = N / RPB;        // 512 blocks per batch
constexpr int   GRID    = B * BPB;        // 2048 blocks = 8192 waves (full residency)
constexpr int   GROUPS  = N / 256;        // 32 groups of 256 candidates

// --- fallback (LDS) geometry (R5 kernel, proven) ---
constexpr int   THREADS2 = 512;
constexpr int   WAVES2   = THREADS2 / 64;
constexpr int   RPW2     = 8;
constexpr int   RPB2     = WAVES2 * RPW2; // 64
constexpr int   BPB2     = N / RPB2;      // 128
constexpr int   GRID2    = B * BPB2;      // 512
constexpr int   TILE2    = 1024;
constexpr int   NTILES2  = N / TILE2;

constexpr size_t PT4_BYTES = (size_t)B * N * sizeof(float4);   // 512 KB
}

typedef __attribute__((ext_vector_type(2))) float f32x2;

#if defined(__has_builtin)
#if __has_builtin(__builtin_elementwise_fma) && __has_builtin(__builtin_elementwise_min)
#define PK_OK 1
#endif
#endif
#ifndef PK_OK
#define PK_OK 0
#endif

__device__ __forceinline__ f32x2 pk2(float a, float b) { f32x2 v; v.x = a; v.y = b; return v; }

__device__ __forceinline__ f32x2 pk_fma(f32x2 a, f32x2 b, f32x2 c) {
#if PK_OK
    return __builtin_elementwise_fma(a, b, c);      // -> v_pk_fma_f32
#else
    f32x2 r; r.x = fmaf(a.x, b.x, c.x); r.y = fmaf(a.y, b.y, c.y); return r;
#endif
}

__device__ __forceinline__ f32x2 pk_min(f32x2 a, f32x2 b) {
#if PK_OK
    return __builtin_elementwise_min(a, b);         // -> v_pk_min_f32
#else
    f32x2 r; r.x = fminf(a.x, b.x); r.y = fminf(a.y, b.y); return r;
#endif
}

__device__ __forceinline__ float rfl(float x) {
    return __int_as_float(__builtin_amdgcn_readfirstlane(__float_as_int(x)));
}

__device__ __forceinline__ float fast_sqrt(float x) {
#if defined(__has_builtin) && __has_builtin(__builtin_amdgcn_sqrtf)
    return __builtin_amdgcn_sqrtf(x);
#else
    return sqrtf(x);
#endif
}

// ---------- prepass: (x,y,z) -> (x,y,z,|p|^2) ----------
__global__ __launch_bounds__(256)
void knn_prep(const float* __restrict__ pc, float4* __restrict__ pt4)
{
    const int i = blockIdx.x * 256 + threadIdx.x;
    if (i < B * N) {
        const float x = pc[3 * i + 0];
        const float y = pc[3 * i + 1];
        const float z = pc[3 * i + 2];
        pt4[i] = make_float4(x, y, z, fmaf(z, z, fmaf(y, y, x * x)));
    }
}

// ---------- per-lane sorted top-4-of-8 ----------
__device__ __forceinline__ void top4_of_8(const float m[8], float L[4])
{
    const float a0 = fminf(m[0], m[1]), b0 = fmaxf(m[0], m[1]);
    const float a1 = fminf(m[2], m[3]), b1 = fmaxf(m[2], m[3]);
    const float a2 = fminf(m[4], m[5]), b2 = fmaxf(m[4], m[5]);
    const float a3 = fminf(m[6], m[7]), b3 = fmaxf(m[6], m[7]);
    const float p0 = fminf(a0, a1), xP = fmaxf(a0, a1), yP = fminf(b0, b1), p3 = fmaxf(b0, b1);
    const float p1 = fminf(xP, yP), p2 = fmaxf(xP, yP);
    const float q0 = fminf(a2, a3), xQ = fmaxf(a2, a3), yQ = fminf(b2, b3), q3 = fmaxf(b2, b3);
    const float q1 = fminf(xQ, yQ), q2 = fmaxf(xQ, yQ);
    const float l0 = fminf(p0, q3), l1 = fminf(p1, q2), l2 = fminf(p2, q1), l3 = fminf(p3, q0);
    const float t0 = fminf(l0, l2), t2 = fmaxf(l0, l2);
    const float t1 = fminf(l1, l3), t3 = fmaxf(l1, l3);
    L[0] = fminf(t0, t1); L[1] = fmaxf(t0, t1);
    L[2] = fminf(t2, t3); L[3] = fmaxf(t2, t3);
}

// ---------- keep-4 merge of two ascending sorted-4 lists (exact tournament) ----------
__device__ __forceinline__ float4 merge44(const float4 a, const float4 b)
{
    const float l0 = fminf(a.x, b.w), l1 = fminf(a.y, b.z);
    const float l2 = fminf(a.z, b.y), l3 = fminf(a.w, b.x);
    const float t0 = fminf(l0, l2), t2 = fmaxf(l0, l2);
    const float t1 = fminf(l1, l3), t3 = fmaxf(l1, l3);
    return make_float4(fminf(t0, t1), fmaxf(t0, t1), fminf(t2, t3), fmaxf(t2, t3));
}

// ---------- legacy merge (fallback kernel only) ----------
template <int NROWS>
__device__ __forceinline__ float merge_and_sum(float L[NROWS][4], const float* qs)
{
#pragma unroll
    for (int r = 0; r < NROWS; ++r) {
        const float p0 = __shfl_xor(L[r][0], 1, 64);
        const float p1 = __shfl_xor(L[r][1], 1, 64);
        const float p2 = __shfl_xor(L[r][2], 1, 64);
        const float p3 = __shfl_xor(L[r][3], 1, 64);
        const float l0 = fminf(L[r][0], p3), l1 = fminf(L[r][1], p2);
        const float l2 = fminf(L[r][2], p1), l3 = fminf(L[r][3], p0);
        const float t0 = fminf(l0, l2), t2 = fmaxf(l0, l2);
        const float t1 = fminf(l1, l3), t3 = fmaxf(l1, l3);
        L[r][0] = fminf(t0, t1); L[r][1] = fmaxf(t0, t1);
        L[r][2] = fminf(t2, t3); L[r][3] = fmaxf(t2, t3);
    }
    float racc[NROWS];
#pragma unroll
    for (int r = 0; r < NROWS; ++r) racc[r] = 0.0f;
#pragma unroll
    for (int k = 0; k < KNN; ++k) {
#pragma unroll
        for (int r = 0; r < NROWS; ++r) {
            float m = L[r][0];
            m = fminf(m, __shfl_xor(m, 2, 64));
            m = fminf(m, __shfl_xor(m, 4, 64));
            m = fminf(m, __shfl_xor(m, 8, 64));
            m = fminf(m, __shfl_xor(m, 16, 64));
            m = fminf(m, __shfl_xor(m, 32, 64));
            racc[r] += fast_sqrt(fmaxf(qs[r] + m, 0.0f) + EPSV);
            const bool take = (L[r][0] == m);
            L[r][0] = take ? L[r][1] : L[r][0];
            L[r][1] = take ? L[r][2] : L[r][1];
            L[r][2] = take ? L[r][3] : L[r][2];
            L[r][3] = take ? FLT_MAX : L[r][3];
        }
    }
    float wsum = 0.0f;
#pragma unroll
    for (int r = 0; r < NROWS; ++r) wsum += racc[r];
    return wsum;
}

// ---------- main kernel: R10 structure + packed-f32 inner loop ----------
template <int ATOMIC>
__global__ __launch_bounds__(THREADS)
void knn_tv_main(const float4* __restrict__ pt4, float* __restrict__ outbuf)
{
    __shared__ float4 sMerge[WAVES][RPW][64];   // 16 KB
    __shared__ float  sWaveSum[WAVES];

    const int tid   = threadIdx.x;
    const int lane  = tid & 63;
    const int wave  = tid >> 6;
    const int blk   = blockIdx.x;
    const int batch = blk / BPB;
    const int row0  = (blk % BPB) * RPB + wave * RPW;

    const float4* __restrict__ b4 = pt4 + (size_t)batch * (size_t)N;

    // query scalars -> SGPR (wave-uniform); packed broadcasts for pk math
    float qs[RPW];
    f32x2 qxp[RPW], qyp[RPW], qzp[RPW];
#pragma unroll
    for (int r = 0; r < RPW; ++r) {
        const float4 q = b4[row0 + r];
        const float nx = rfl(-2.0f * q.x);
        const float ny = rfl(-2.0f * q.y);
        const float nz = rfl(-2.0f * q.z);
        qs[r]  = rfl(q.w);
        qxp[r] = pk2(nx, nx);
        qyp[r] = pk2(ny, ny);
        qzp[r] = pk2(nz, nz);
    }

    // packed per-(lane, slot) stream minima: 4 packed slots = 8 scalar streams/row
    f32x2 m0p[RPW][4];
#pragma unroll
    for (int r = 0; r < RPW; ++r)
#pragma unroll
        for (int j = 0; j < 4; ++j)
            m0p[r][j] = pk2(FLT_MAX, FLT_MAX);

    // 32 groups of 256 candidates; packed pairs (c0,c1),(c2,c3); slot index q is
    // COMPILE-TIME (rule #20). unroll 2 for load pipelining (R9/R10-proven).
    const float4* __restrict__ p = b4 + lane;
#pragma unroll 2
    for (int gg = 0; gg < GROUPS / 4; ++gg) {
#pragma unroll
        for (int q = 0; q < 4; ++q) {
            const int off = (gg * 4 + q) * 256;
            const float4 a0 = p[off +   0];
            const float4 a1 = p[off +  64];
            const float4 a2 = p[off + 128];
            const float4 a3 = p[off + 192];
            const f32x2 cx01 = pk2(a0.x, a1.x), cx23 = pk2(a2.x, a3.x);
            const f32x2 cy01 = pk2(a0.y, a1.y), cy23 = pk2(a2.y, a3.y);
            const f32x2 cz01 = pk2(a0.z, a1.z), cz23 = pk2(a2.z, a3.z);
            const f32x2 cs01 = pk2(a0.w, a1.w), cs23 = pk2(a2.w, a3.w);
#pragma unroll
            for (int r = 0; r < RPW; ++r) {
                const f32x2 v01 = pk_fma(cx01, qxp[r],
                                  pk_fma(cy01, qyp[r],
                                  pk_fma(cz01, qzp[r], cs01)));
                const f32x2 v23 = pk_fma(cx23, qxp[r],
                                  pk_fma(cy23, qyp[r],
                                  pk_fma(cz23, qzp[r], cs23)));
                m0p[r][q] = pk_min(m0p[r][q], pk_min(v01, v23));
            }
        }
    }

    // unpack + per-lane sorted top-4 per row, stash to LDS for the transpose
#pragma unroll
    for (int r = 0; r < RPW; ++r) {
        const float m[8] = { m0p[r][0].x, m0p[r][0].y, m0p[r][1].x, m0p[r][1].y,
                             m0p[r][2].x, m0p[r][2].y, m0p[r][3].x, m0p[r][3].y };
        float L4[4];
        top4_of_8(m, L4);
        sMerge[wave][r][lane] = make_float4(L4[0], L4[1], L4[2], L4[3]);
    }
    __syncthreads();

    // quarter qr (16 lanes) owns row qr: gather 4 lists -> exact top-4-of-16,
    // then 16 pops with 4-step butterflies (all 4 rows pop concurrently).
    const int qr = lane >> 4;
    const int j  = lane & 15;
    const float4 A  = sMerge[wave][qr][j];
    const float4 Bv = sMerge[wave][qr][j + 16];
    const float4 C  = sMerge[wave][qr][j + 32];
    const float4 D  = sMerge[wave][qr][j + 48];
    const float4 G  = merge44(merge44(A, Bv), merge44(C, D));

    // qs[quarter] via static-index lane-bit selects (rule #20)
    const float qs01 = (lane & 16) ? qs[1] : qs[0];
    const float qs23 = (lane & 16) ? qs[3] : qs[2];
    const float qsq  = (lane & 32) ? qs23 : qs01;

    float G0 = G.x, G1 = G.y, G2 = G.z, G3 = G.w;
    float rsum = 0.0f;
#pragma unroll
    for (int k = 0; k < KNN; ++k) {
        float m = G0;
        m = fminf(m, __shfl_xor(m, 1, 64));
        m = fminf(m, __shfl_xor(m, 2, 64));
        m = fminf(m, __shfl_xor(m, 4, 64));
        m = fminf(m, __shfl_xor(m, 8, 64));
        rsum += fast_sqrt(fmaxf(qsq + m, 0.0f) + EPSV);
        const bool take = (G0 == m);
        G0 = take ? G1 : G0;
        G1 = take ? G2 : G1;
        G2 = take ? G3 : G2;
        G3 = take ? FLT_MAX : G3;
    }

    float tot = rsum + __shfl_xor(rsum, 16, 64);
    tot += __shfl_xor(tot, 32, 64);

    if (lane == 0) sWaveSum[wave] = tot;
    __syncthreads();
    if (tid == 0) {
        float t = 0.0f;
#pragma unroll
        for (int w = 0; w < WAVES; ++w) t += sWaveSum[w];
        if (ATOMIC) atomicAdd(outbuf, t * (1.0f / (float)(B * N)));
        else        outbuf[blk] = t;
    }
}

// ---------- fallback: R5's LDS-staged kernel (proven, unchanged) ----------
template <int ATOMIC>
__global__ __launch_bounds__(THREADS2)
__attribute__((amdgpu_waves_per_eu(2, 4)))
void knn_tv_lds(const float* __restrict__ pc, float* __restrict__ outbuf)
{
    __shared__ float sX[TILE2], sY[TILE2], sZ[TILE2], sS[TILE2];
    __shared__ float sWaveSum[WAVES2];

    const int tid   = threadIdx.x;
    const int lane  = tid & 63;
    const int wave  = tid >> 6;
    const int blk   = blockIdx.x;
    const int batch = blk / BPB2;
    const int row0  = (blk % BPB2) * RPB2 + wave * RPW2;

    const float* __restrict__ base = pc + (size_t)batch * (size_t)N * 3;

    float qx[RPW2], qy[RPW2], qz[RPW2], qs[RPW2];
#pragma unroll
    for (int r = 0; r < RPW2; ++r) {
        const int row = row0 + r;
        const float x = base[row * 3 + 0];
        const float y = base[row * 3 + 1];
        const float z = base[row * 3 + 2];
        qx[r] = rfl(-2.0f * x); qy[r] = rfl(-2.0f * y); qz[r] = rfl(-2.0f * z);
        qs[r] = rfl(fmaf(z, z, fmaf(y, y, x * x)));
    }

    float m0[RPW2][8];
#pragma unroll
    for (int r = 0; r < RPW2; ++r)
#pragma unroll
        for (int c = 0; c < 8; ++c) m0[r][c] = FLT_MAX;

    for (int tile = 0; tile < NTILES2; ++tile) {
        __syncthreads();
#pragma unroll
        for (int h = 0; h < 2; ++h) {
            const int p  = tid + h * THREADS2;
            const int gp = tile * TILE2 + p;
            const float x = base[gp * 3 + 0];
            const float y = base[gp * 3 + 1];
            const float z = base[gp * 3 + 2];
            sX[p] = x; sY[p] = y; sZ[p] = z;
            sS[p] = fmaf(z, z, fmaf(y, y, x * x));
        }
        __syncthreads();

#pragma unroll
        for (int grp = 0; grp < 4; ++grp) {
            const int o = grp * 256 + 4 * lane;
            const float4 CX = *(const float4*)&sX[o];
            const float4 CY = *(const float4*)&sY[o];
            const float4 CZ = *(const float4*)&sZ[o];
            const float4 CS = *(const float4*)&sS[o];
            const float cx[4] = {CX.x, CX.y, CX.z, CX.w};
            const float cy[4] = {CY.x, CY.y, CY.z, CY.w};
            const float cz[4] = {CZ.x, CZ.y, CZ.z, CZ.w};
            const float cs[4] = {CS.x, CS.y, CS.z, CS.w};
            const int jb = (grp & 1) * 4;
#pragma unroll
            for (int r = 0; r < RPW2; ++r)
#pragma unroll
                for (int i = 0; i < 4; ++i) {
                    const float v = fmaf(cx[i], qx[r], fmaf(cy[i], qy[r], fmaf(cz[i], qz[r], cs[i])));
                    m0[r][jb + i] = fminf(m0[r][jb + i], v);
                }
        }
    }

    float L[RPW2][4];
#pragma unroll
    for (int r = 0; r < RPW2; ++r) top4_of_8(m0[r], L[r]);

    const float wsum = merge_and_sum<RPW2>(L, qs);

    if (lane == 0) sWaveSum[wave] = wsum;
    __syncthreads();
    if (tid == 0) {
        float t = 0.0f;
#pragma unroll
        for (int w = 0; w < WAVES2; ++w) t += sWaveSum[w];
        if (ATOMIC) atomicAdd(outbuf, t * (1.0f / (float)(B * N)));
        else        outbuf[blk] = t;
    }
}

__global__ __launch_bounds__(256)
void knn_tv_reduce(const float* __restrict__ partial, float* __restrict__ out, int n)
{
    __shared__ float s[4];
    const int tid = threadIdx.x;
    float v = 0.0f;
    for (int i = tid; i < n; i += 256) v += partial[i];
#pragma unroll
    for (int off = 1; off < 64; off <<= 1) v += __shfl_xor(v, off, 64);
    if ((tid & 63) == 0) s[tid >> 6] = v;
    __syncthreads();
    if (tid == 0) {
        const float t = s[0] + s[1] + s[2] + s[3];
        out[0] = t * (1.0f / (float)(B * N));
    }
}

extern "C" void kernel_launch(void* const* d_in, const int* in_sizes, int n_in,
                              void* d_out, int out_size, void* d_ws, size_t ws_size,
                              hipStream_t stream)
{
    const float* pc  = (const float*)d_in[0];
    float*       out = (float*)d_out;

    if (ws_size >= PT4_BYTES + GRID * sizeof(float)) {
        float4* pt4     = (float4*)d_ws;
        float*  partial = (float*)((char*)d_ws + PT4_BYTES);
        knn_prep<<<(B * N + 255) / 256, 256, 0, stream>>>(pc, pt4);
        knn_tv_main<0><<<GRID, THREADS, 0, stream>>>(pt4, partial);
        knn_tv_reduce<<<1, 256, 0, stream>>>(partial, out, GRID);
    } else if (ws_size >= GRID2 * sizeof(float)) {
        float* partial = (float*)d_ws;
        knn_tv_lds<0><<<GRID2, THREADS2, 0, stream>>>(pc, partial);
        knn_tv_reduce<<<1, 256, 0, stream>>>(partial, out, GRID2);
    } else {
        hipMemsetAsync(d_out, 0, sizeof(float), stream);
        knn_tv_lds<1><<<GRID2, THREADS2, 0, stream>>>(pc, out);
    }
}

// Round 14
// 50.681 us; speedup vs baseline: 1.1751x; 1.0720x over previous
//
#include <hip/hip_runtime.h>
#include <cfloat>
#include <math.h>

namespace {
constexpr int   B      = 4;
constexpr int   N      = 8192;
constexpr int   KNN    = 16;
constexpr float EPSV   = 1e-12f;

// --- main kernel geometry: 4-wave blocks, 8 rows/wave (fp32) ---
constexpr int   THREADS = 256;            // 4 waves
constexpr int   WAVES   = THREADS / 64;   // 4
constexpr int   RPW     = 8;              // query rows per wave == 8 eighths
constexpr int   RPB     = WAVES * RPW;    // 32 rows per block
constexpr int   BPB     = N / RPB;        // 256 blocks per batch
constexpr int   GRID    = B * BPB;        // 1024 blocks = 4096 waves
constexpr int   GROUPS  = N / 256;        // 32 groups of 256 candidates

// --- fallback (LDS) geometry (R5 kernel, proven) ---
constexpr int   THREADS2 = 512;
constexpr int   WAVES2   = THREADS2 / 64;
constexpr int   RPW2     = 8;
constexpr int   RPB2     = WAVES2 * RPW2; // 64
constexpr int   BPB2     = N / RPB2;      // 128
constexpr int   GRID2    = B * BPB2;      // 512
constexpr int   TILE2    = 1024;
constexpr int   NTILES2  = N / TILE2;

constexpr size_t PT4_BYTES = (size_t)B * N * sizeof(float4);   // 512 KB
}

__device__ __forceinline__ float rfl(float x) {
    return __int_as_float(__builtin_amdgcn_readfirstlane(__float_as_int(x)));
}

__device__ __forceinline__ float fast_sqrt(float x) {
#if defined(__has_builtin) && __has_builtin(__builtin_amdgcn_sqrtf)
    return __builtin_amdgcn_sqrtf(x);
#else
    return sqrtf(x);
#endif
}

// ---------- prepass: (x,y,z) -> (x,y,z,|p|^2) ----------
__global__ __launch_bounds__(256)
void knn_prep(const float* __restrict__ pc, float4* __restrict__ pt4)
{
    const int i = blockIdx.x * 256 + threadIdx.x;
    if (i < B * N) {
        const float x = pc[3 * i + 0];
        const float y = pc[3 * i + 1];
        const float z = pc[3 * i + 2];
        pt4[i] = make_float4(x, y, z, fmaf(z, z, fmaf(y, y, x * x)));
    }
}

// ---------- per-lane sorted top-4-of-8 ----------
__device__ __forceinline__ void top4_of_8(const float m[8], float L[4])
{
    const float a0 = fminf(m[0], m[1]), b0 = fmaxf(m[0], m[1]);
    const float a1 = fminf(m[2], m[3]), b1 = fmaxf(m[2], m[3]);
    const float a2 = fminf(m[4], m[5]), b2 = fmaxf(m[4], m[5]);
    const float a3 = fminf(m[6], m[7]), b3 = fmaxf(m[6], m[7]);
    const float p0 = fminf(a0, a1), xP = fmaxf(a0, a1), yP = fminf(b0, b1), p3 = fmaxf(b0, b1);
    const float p1 = fminf(xP, yP), p2 = fmaxf(xP, yP);
    const float q0 = fminf(a2, a3), xQ = fmaxf(a2, a3), yQ = fminf(b2, b3), q3 = fmaxf(b2, b3);
    const float q1 = fminf(xQ, yQ), q2 = fmaxf(xQ, yQ);
    const float l0 = fminf(p0, q3), l1 = fminf(p1, q2), l2 = fminf(p2, q1), l3 = fminf(p3, q0);
    const float t0 = fminf(l0, l2), t2 = fmaxf(l0, l2);
    const float t1 = fminf(l1, l3), t3 = fmaxf(l1, l3);
    L[0] = fminf(t0, t1); L[1] = fmaxf(t0, t1);
    L[2] = fminf(t2, t3); L[3] = fmaxf(t2, t3);
}

// ---------- keep-4 merge of two ascending sorted-4 lists (exact tournament) ----------
__device__ __forceinline__ float4 merge44(const float4 a, const float4 b)
{
    const float l0 = fminf(a.x, b.w), l1 = fminf(a.y, b.z);
    const float l2 = fminf(a.z, b.y), l3 = fminf(a.w, b.x);
    const float t0 = fminf(l0, l2), t2 = fmaxf(l0, l2);
    const float t1 = fminf(l1, l3), t3 = fmaxf(l1, l3);
    return make_float4(fminf(t0, t1), fmaxf(t0, t1), fminf(t2, t3), fmaxf(t2, t3));
}

// ---------- legacy merge (fallback kernel only) ----------
template <int NROWS>
__device__ __forceinline__ float merge_and_sum(float L[NROWS][4], const float* qs)
{
#pragma unroll
    for (int r = 0; r < NROWS; ++r) {
        const float p0 = __shfl_xor(L[r][0], 1, 64);
        const float p1 = __shfl_xor(L[r][1], 1, 64);
        const float p2 = __shfl_xor(L[r][2], 1, 64);
        const float p3 = __shfl_xor(L[r][3], 1, 64);
        const float l0 = fminf(L[r][0], p3), l1 = fminf(L[r][1], p2);
        const float l2 = fminf(L[r][2], p1), l3 = fminf(L[r][3], p0);
        const float t0 = fminf(l0, l2), t2 = fmaxf(l0, l2);
        const float t1 = fminf(l1, l3), t3 = fmaxf(l1, l3);
        L[r][0] = fminf(t0, t1); L[r][1] = fmaxf(t0, t1);
        L[r][2] = fminf(t2, t3); L[r][3] = fmaxf(t2, t3);
    }
    float racc[NROWS];
#pragma unroll
    for (int r = 0; r < NROWS; ++r) racc[r] = 0.0f;
#pragma unroll
    for (int k = 0; k < KNN; ++k) {
#pragma unroll
        for (int r = 0; r < NROWS; ++r) {
            float m = L[r][0];
            m = fminf(m, __shfl_xor(m, 2, 64));
            m = fminf(m, __shfl_xor(m, 4, 64));
            m = fminf(m, __shfl_xor(m, 8, 64));
            m = fminf(m, __shfl_xor(m, 16, 64));
            m = fminf(m, __shfl_xor(m, 32, 64));
            racc[r] += fast_sqrt(fmaxf(qs[r] + m, 0.0f) + EPSV);
            const bool take = (L[r][0] == m);
            L[r][0] = take ? L[r][1] : L[r][0];
            L[r][1] = take ? L[r][2] : L[r][1];
            L[r][2] = take ? L[r][3] : L[r][2];
            L[r][3] = take ? FLT_MAX : L[r][3];
        }
    }
    float wsum = 0.0f;
#pragma unroll
    for (int r = 0; r < NROWS; ++r) wsum += racc[r];
    return wsum;
}

// ---------- main kernel: fp32, 8 rows/wave, eighth-merge ----------
__global__ __launch_bounds__(THREADS)
__attribute__((amdgpu_waves_per_eu(2, 4)))   // cap 256 VGPR (proven honored): ~120 live, no spill
void knn_tv_main8(const float4* __restrict__ pt4, float* __restrict__ outbuf)
{
    __shared__ float4 sMerge[WAVES][RPW][64];   // 32 KB
    __shared__ float  sWaveSum[WAVES];

    const int tid   = threadIdx.x;
    const int lane  = tid & 63;
    const int wave  = tid >> 6;
    const int blk   = blockIdx.x;
    const int batch = blk / BPB;
    const int row0  = (blk % BPB) * RPB + wave * RPW;

    const float4* __restrict__ b4 = pt4 + (size_t)batch * (size_t)N;

    // query scalars -> SGPR (wave-uniform); fold -2 into q, re-add |q|^2 at pop
    float qx[RPW], qy[RPW], qz[RPW], qs[RPW];
#pragma unroll
    for (int r = 0; r < RPW; ++r) {
        const float4 q = b4[row0 + r];
        qx[r] = rfl(-2.0f * q.x);
        qy[r] = rfl(-2.0f * q.y);
        qz[r] = rfl(-2.0f * q.z);
        qs[r] = rfl(q.w);
    }

    // per-(lane, slot) stream minima of v = |c|^2 - 2 q.c  (8 slots/lane = 512 streams/row)
    float m0[RPW][8];
#pragma unroll
    for (int r = 0; r < RPW; ++r)
#pragma unroll
        for (int j = 0; j < 8; ++j)
            m0[r][j] = FLT_MAX;

    // R9/R10-proven scan shape: 4 loads in flight/group, static min3 slot pair
    // (rule #20), unroll 2 for load pipelining. Each 16B load feeds 8 rows.
    const float4* __restrict__ p = b4 + lane;
#pragma unroll 2
    for (int gg = 0; gg < GROUPS / 4; ++gg) {
#pragma unroll
        for (int q = 0; q < 4; ++q) {
            const int off = (gg * 4 + q) * 256;
            const float4 a0 = p[off +   0];
            const float4 a1 = p[off +  64];
            const float4 a2 = p[off + 128];
            const float4 a3 = p[off + 192];
#pragma unroll
            for (int r = 0; r < RPW; ++r) {
                const float v0 = fmaf(a0.x, qx[r], fmaf(a0.y, qy[r], fmaf(a0.z, qz[r], a0.w)));
                const float v1 = fmaf(a1.x, qx[r], fmaf(a1.y, qy[r], fmaf(a1.z, qz[r], a1.w)));
                const float v2 = fmaf(a2.x, qx[r], fmaf(a2.y, qy[r], fmaf(a2.z, qz[r], a2.w)));
                const float v3 = fmaf(a3.x, qx[r], fmaf(a3.y, qy[r], fmaf(a3.z, qz[r], a3.w)));
                m0[r][2 * q + 0] = fminf(m0[r][2 * q + 0], fminf(v0, v1));   // v_min3_f32
                m0[r][2 * q + 1] = fminf(m0[r][2 * q + 1], fminf(v2, v3));   // v_min3_f32
            }
        }
    }

    // stash per-lane sorted top-4 per row
#pragma unroll
    for (int r = 0; r < RPW; ++r) {
        float L4[4];
        top4_of_8(m0[r], L4);
        sMerge[wave][r][lane] = make_float4(L4[0], L4[1], L4[2], L4[3]);
    }
    __syncthreads();

    // eighth e (8 lanes) owns row e: gather 8 lists -> exact top-4-of-32, then
    // 16 pops with 3-step butterflies (one pop loop serves all 8 rows).
    const int e = lane >> 3;
    const int j = lane & 7;
    float4 g[8];
#pragma unroll
    for (int t = 0; t < 8; ++t) g[t] = sMerge[wave][e][j + 8 * t];
    const float4 G = merge44(merge44(merge44(g[0], g[1]), merge44(g[2], g[3])),
                             merge44(merge44(g[4], g[5]), merge44(g[6], g[7])));

    // qs[e] via static-index lane-bit mux (rule #20)
    const float qsa = (lane & 8) ? qs[1] : qs[0];
    const float qsb = (lane & 8) ? qs[3] : qs[2];
    const float qsc = (lane & 8) ? qs[5] : qs[4];
    const float qsd = (lane & 8) ? qs[7] : qs[6];
    const float qse = (lane & 16) ? qsb : qsa;
    const float qsf = (lane & 16) ? qsd : qsc;
    const float qsq = (lane & 32) ? qsf : qse;

    float G0 = G.x, G1 = G.y, G2 = G.z, G3 = G.w;
    float rsum = 0.0f;
#pragma unroll
    for (int k = 0; k < KNN; ++k) {
        float m = G0;
        m = fminf(m, __shfl_xor(m, 1, 64));
        m = fminf(m, __shfl_xor(m, 2, 64));
        m = fminf(m, __shfl_xor(m, 4, 64));
        rsum += fast_sqrt(fmaxf(qsq + m, 0.0f) + EPSV);
        const bool take = (G0 == m);
        G0 = take ? G1 : G0;
        G1 = take ? G2 : G1;
        G2 = take ? G3 : G2;
        G3 = take ? FLT_MAX : G3;
    }

    // combine rows: xor 8/16/32 sums across the 8 eighths
    float tot = rsum + __shfl_xor(rsum, 8, 64);
    tot += __shfl_xor(tot, 16, 64);
    tot += __shfl_xor(tot, 32, 64);

    if (lane == 0) sWaveSum[wave] = tot;
    __syncthreads();
    if (tid == 0) {
        float t = 0.0f;
#pragma unroll
        for (int w = 0; w < WAVES; ++w) t += sWaveSum[w];
        outbuf[blk] = t;
    }
}

// ---------- fallback: R5's LDS-staged kernel (proven, unchanged) ----------
template <int ATOMIC>
__global__ __launch_bounds__(THREADS2)
__attribute__((amdgpu_waves_per_eu(2, 4)))
void knn_tv_lds(const float* __restrict__ pc, float* __restrict__ outbuf)
{
    __shared__ float sX[TILE2], sY[TILE2], sZ[TILE2], sS[TILE2];
    __shared__ float sWaveSum[WAVES2];

    const int tid   = threadIdx.x;
    const int lane  = tid & 63;
    const int wave  = tid >> 6;
    const int blk   = blockIdx.x;
    const int batch = blk / BPB2;
    const int row0  = (blk % BPB2) * RPB2 + wave * RPW2;

    const float* __restrict__ base = pc + (size_t)batch * (size_t)N * 3;

    float qx[RPW2], qy[RPW2], qz[RPW2], qs[RPW2];
#pragma unroll
    for (int r = 0; r < RPW2; ++r) {
        const int row = row0 + r;
        const float x = base[row * 3 + 0];
        const float y = base[row * 3 + 1];
        const float z = base[row * 3 + 2];
        qx[r] = rfl(-2.0f * x); qy[r] = rfl(-2.0f * y); qz[r] = rfl(-2.0f * z);
        qs[r] = rfl(fmaf(z, z, fmaf(y, y, x * x)));
    }

    float m0[RPW2][8];
#pragma unroll
    for (int r = 0; r < RPW2; ++r)
#pragma unroll
        for (int c = 0; c < 8; ++c) m0[r][c] = FLT_MAX;

    for (int tile = 0; tile < NTILES2; ++tile) {
        __syncthreads();
#pragma unroll
        for (int h = 0; h < 2; ++h) {
            const int p  = tid + h * THREADS2;
            const int gp = tile * TILE2 + p;
            const float x = base[gp * 3 + 0];
            const float y = base[gp * 3 + 1];
            const float z = base[gp * 3 + 2];
            sX[p] = x; sY[p] = y; sZ[p] = z;
            sS[p] = fmaf(z, z, fmaf(y, y, x * x));
        }
        __syncthreads();

#pragma unroll
        for (int grp = 0; grp < 4; ++grp) {
            const int o = grp * 256 + 4 * lane;
            const float4 CX = *(const float4*)&sX[o];
            const float4 CY = *(const float4*)&sY[o];
            const float4 CZ = *(const float4*)&sZ[o];
            const float4 CS = *(const float4*)&sS[o];
            const float cx[4] = {CX.x, CX.y, CX.z, CX.w};
            const float cy[4] = {CY.x, CY.y, CY.z, CY.w};
            const float cz[4] = {CZ.x, CZ.y, CZ.z, CZ.w};
            const float cs[4] = {CS.x, CS.y, CS.z, CS.w};
            const int jb = (grp & 1) * 4;
#pragma unroll
            for (int r = 0; r < RPW2; ++r)
#pragma unroll
                for (int i = 0; i < 4; ++i) {
                    const float v = fmaf(cx[i], qx[r], fmaf(cy[i], qy[r], fmaf(cz[i], qz[r], cs[i])));
                    m0[r][jb + i] = fminf(m0[r][jb + i], v);
                }
        }
    }

    float L[RPW2][4];
#pragma unroll
    for (int r = 0; r < RPW2; ++r) top4_of_8(m0[r], L[r]);

    const float wsum = merge_and_sum<RPW2>(L, qs);

    if (lane == 0) sWaveSum[wave] = wsum;
    __syncthreads();
    if (tid == 0) {
        float t = 0.0f;
#pragma unroll
        for (int w = 0; w < WAVES2; ++w) t += sWaveSum[w];
        if (ATOMIC) atomicAdd(outbuf, t * (1.0f / (float)(B * N)));
        else        outbuf[blk] = t;
    }
}

__global__ __launch_bounds__(256)
void knn_tv_reduce(const float* __restrict__ partial, float* __restrict__ out, int n)
{
    __shared__ float s[4];
    const int tid = threadIdx.x;
    float v = 0.0f;
    for (int i = tid; i < n; i += 256) v += partial[i];
#pragma unroll
    for (int off = 1; off < 64; off <<= 1) v += __shfl_xor(v, off, 64);
    if ((tid & 63) == 0) s[tid >> 6] = v;
    __syncthreads();
    if (tid == 0) {
        const float t = s[0] + s[1] + s[2] + s[3];
        out[0] = t * (1.0f / (float)(B * N));
    }
}

extern "C" void kernel_launch(void* const* d_in, const int* in_sizes, int n_in,
                              void* d_out, int out_size, void* d_ws, size_t ws_size,
                              hipStream_t stream)
{
    const float* pc  = (const float*)d_in[0];
    float*       out = (float*)d_out;

    if (ws_size >= PT4_BYTES + GRID * sizeof(float)) {
        float4* pt4     = (float4*)d_ws;
        float*  partial = (float*)((char*)d_ws + PT4_BYTES);
        knn_prep<<<(B * N + 255) / 256, 256, 0, stream>>>(pc, pt4);
        knn_tv_main8<<<GRID, THREADS, 0, stream>>>(pt4, partial);
        knn_tv_reduce<<<1, 256, 0, stream>>>(partial, out, GRID);
    } else if (ws_size >= GRID2 * sizeof(float)) {
        float* partial = (float*)d_ws;
        knn_tv_lds<0><<<GRID2, THREADS2, 0, stream>>>(pc, partial);
        knn_tv_reduce<<<1, 256, 0, stream>>>(partial, out, GRID2);
    } else {
        hipMemsetAsync(d_out, 0, sizeof(float), stream);
        knn_tv_lds<1><<<GRID2, THREADS2, 0, stream>>>(pc, out);
    }
}

// Round 15
// 47.173 us; speedup vs baseline: 1.2625x; 1.0744x over previous
//
#include <hip/hip_runtime.h>
#include <cfloat>
#include <math.h>

namespace {
constexpr int   B      = 4;
constexpr int   N      = 8192;
constexpr int   KNN    = 16;
constexpr float EPSV   = 1e-12f;

// --- main kernel: 4-wave blocks, 16 rows/block, candidate-split halves ---
constexpr int   THREADS = 256;            // 4 waves
constexpr int   WAVES   = THREADS / 64;   // 4
constexpr int   RPW     = 8;              // rows per wave (waves 0&2 share rows, halves differ)
constexpr int   RPB     = 16;             // rows per block
constexpr int   BPB     = N / RPB;        // 512 blocks per batch
constexpr int   GRID    = B * BPB;        // 2048 blocks = 8192 waves
constexpr int   HALF    = N / 2;          // 4096 candidates per half
constexpr int   GG      = 4;              // 4 outer iters x 4 subgroups of 256 = 4096

// --- fallback (LDS) geometry (R5 kernel, proven) ---
constexpr int   THREADS2 = 512;
constexpr int   WAVES2   = THREADS2 / 64;
constexpr int   RPW2     = 8;
constexpr int   RPB2     = WAVES2 * RPW2; // 64
constexpr int   BPB2     = N / RPB2;      // 128
constexpr int   GRID2    = B * BPB2;      // 512
constexpr int   TILE2    = 1024;
constexpr int   NTILES2  = N / TILE2;

constexpr size_t PT4_BYTES = (size_t)B * N * sizeof(float4);   // 512 KB
}

__device__ __forceinline__ float rfl(float x) {
    return __int_as_float(__builtin_amdgcn_readfirstlane(__float_as_int(x)));
}

__device__ __forceinline__ float fast_sqrt(float x) {
#if defined(__has_builtin) && __has_builtin(__builtin_amdgcn_sqrtf)
    return __builtin_amdgcn_sqrtf(x);
#else
    return sqrtf(x);
#endif
}

// ---------- prepass: (x,y,z) -> (x,y,z,|p|^2) ----------
__global__ __launch_bounds__(256)
void knn_prep(const float* __restrict__ pc, float4* __restrict__ pt4)
{
    const int i = blockIdx.x * 256 + threadIdx.x;
    if (i < B * N) {
        const float x = pc[3 * i + 0];
        const float y = pc[3 * i + 1];
        const float z = pc[3 * i + 2];
        pt4[i] = make_float4(x, y, z, fmaf(z, z, fmaf(y, y, x * x)));
    }
}

// ---------- exact ascending sort of 4 values ----------
__device__ __forceinline__ float4 sort4(const float m[4])
{
    const float a = fminf(m[0], m[1]), b = fmaxf(m[0], m[1]);
    const float c = fminf(m[2], m[3]), d = fmaxf(m[2], m[3]);
    const float l0 = fminf(a, c), t = fmaxf(a, c);
    const float l3 = fmaxf(b, d), u = fminf(b, d);
    return make_float4(l0, fminf(t, u), fmaxf(t, u), l3);
}

// ---------- keep-4 merge of two ascending sorted-4 lists (exact) ----------
__device__ __forceinline__ float4 merge44(const float4 a, const float4 b)
{
    const float l0 = fminf(a.x, b.w), l1 = fminf(a.y, b.z);
    const float l2 = fminf(a.z, b.y), l3 = fminf(a.w, b.x);
    const float t0 = fminf(l0, l2), t2 = fmaxf(l0, l2);
    const float t1 = fminf(l1, l3), t3 = fmaxf(l1, l3);
    return make_float4(fminf(t0, t1), fmaxf(t0, t1), fminf(t2, t3), fmaxf(t2, t3));
}

// ---------- helpers reused by fallback ----------
__device__ __forceinline__ void top4_of_8(const float m[8], float L[4])
{
    const float a0 = fminf(m[0], m[1]), b0 = fmaxf(m[0], m[1]);
    const float a1 = fminf(m[2], m[3]), b1 = fmaxf(m[2], m[3]);
    const float a2 = fminf(m[4], m[5]), b2 = fmaxf(m[4], m[5]);
    const float a3 = fminf(m[6], m[7]), b3 = fmaxf(m[6], m[7]);
    const float p0 = fminf(a0, a1), xP = fmaxf(a0, a1), yP = fminf(b0, b1), p3 = fmaxf(b0, b1);
    const float p1 = fminf(xP, yP), p2 = fmaxf(xP, yP);
    const float q0 = fminf(a2, a3), xQ = fmaxf(a2, a3), yQ = fminf(b2, b3), q3 = fmaxf(b2, b3);
    const float q1 = fminf(xQ, yQ), q2 = fmaxf(xQ, yQ);
    const float l0 = fminf(p0, q3), l1 = fminf(p1, q2), l2 = fminf(p2, q1), l3 = fminf(p3, q0);
    const float t0 = fminf(l0, l2), t2 = fmaxf(l0, l2);
    const float t1 = fminf(l1, l3), t3 = fmaxf(l1, l3);
    L[0] = fminf(t0, t1); L[1] = fmaxf(t0, t1);
    L[2] = fminf(t2, t3); L[3] = fmaxf(t2, t3);
}

template <int NROWS>
__device__ __forceinline__ float merge_and_sum(float L[NROWS][4], const float* qs)
{
#pragma unroll
    for (int r = 0; r < NROWS; ++r) {
        const float p0 = __shfl_xor(L[r][0], 1, 64);
        const float p1 = __shfl_xor(L[r][1], 1, 64);
        const float p2 = __shfl_xor(L[r][2], 1, 64);
        const float p3 = __shfl_xor(L[r][3], 1, 64);
        const float l0 = fminf(L[r][0], p3), l1 = fminf(L[r][1], p2);
        const float l2 = fminf(L[r][2], p1), l3 = fminf(L[r][3], p0);
        const float t0 = fminf(l0, l2), t2 = fmaxf(l0, l2);
        const float t1 = fminf(l1, l3), t3 = fmaxf(l1, l3);
        L[r][0] = fminf(t0, t1); L[r][1] = fmaxf(t0, t1);
        L[r][2] = fminf(t2, t3); L[r][3] = fmaxf(t2, t3);
    }
    float racc[NROWS];
#pragma unroll
    for (int r = 0; r < NROWS; ++r) racc[r] = 0.0f;
#pragma unroll
    for (int k = 0; k < KNN; ++k) {
#pragma unroll
        for (int r = 0; r < NROWS; ++r) {
            float m = L[r][0];
            m = fminf(m, __shfl_xor(m, 2, 64));
            m = fminf(m, __shfl_xor(m, 4, 64));
            m = fminf(m, __shfl_xor(m, 8, 64));
            m = fminf(m, __shfl_xor(m, 16, 64));
            m = fminf(m, __shfl_xor(m, 32, 64));
            racc[r] += fast_sqrt(fmaxf(qs[r] + m, 0.0f) + EPSV);
            const bool take = (L[r][0] == m);
            L[r][0] = take ? L[r][1] : L[r][0];
            L[r][1] = take ? L[r][2] : L[r][1];
            L[r][2] = take ? L[r][3] : L[r][2];
            L[r][3] = take ? FLT_MAX : L[r][3];
        }
    }
    float wsum = 0.0f;
#pragma unroll
    for (int r = 0; r < NROWS; ++r) wsum += racc[r];
    return wsum;
}

// ---------- main kernel: candidate-split, 8192 waves, lean VGPR ----------
__global__ __launch_bounds__(THREADS)
void knn_tv_split(const float4* __restrict__ pt4, float* __restrict__ outbuf)
{
    __shared__ float4 sMerge[WAVES][RPW][64];   // 32 KB
    __shared__ float  sWaveSum[2];

    const int tid   = threadIdx.x;
    const int lane  = tid & 63;
    const int wave  = tid >> 6;
    const int half  = wave >> 1;              // candidate half (0/1)
    const int wrow  = wave & 1;               // row sub-block (0/1)
    const int blk   = blockIdx.x;
    const int batch = blk / BPB;
    const int row0  = (blk % BPB) * RPB + wrow * RPW;

    const float4* __restrict__ b4 = pt4 + (size_t)batch * (size_t)N;

    // query scalars -> SGPR (wave-uniform); fold -2 into q, re-add |q|^2 at pop
    float qx[RPW], qy[RPW], qz[RPW], qs[RPW];
#pragma unroll
    for (int r = 0; r < RPW; ++r) {
        const float4 q = b4[row0 + r];
        qx[r] = rfl(-2.0f * q.x);
        qy[r] = rfl(-2.0f * q.y);
        qz[r] = rfl(-2.0f * q.z);
        qs[r] = rfl(q.w);
    }

    // 4 slots/lane; stream stats: 2 waves x 64 lanes x 4 slots = 512 streams/row, depth 16
    float m0[RPW][4];
#pragma unroll
    for (int r = 0; r < RPW; ++r)
#pragma unroll
        for (int j = 0; j < 4; ++j)
            m0[r][j] = FLT_MAX;

    // scan this wave's candidate half: 16 subgroups of 256 (GG=4 outer x 4 inner).
    // slot pair (q&1)*2 is COMPILE-TIME (rule #20); unroll 2 outer for pipelining.
    const float4* __restrict__ p = b4 + half * HALF + lane;
#pragma unroll 2
    for (int gg = 0; gg < GG; ++gg) {
#pragma unroll
        for (int q = 0; q < 4; ++q) {
            const int off = (gg * 4 + q) * 256;
            const float4 a0 = p[off +   0];
            const float4 a1 = p[off +  64];
            const float4 a2 = p[off + 128];
            const float4 a3 = p[off + 192];
            const int s0 = (q & 1) * 2;
#pragma unroll
            for (int r = 0; r < RPW; ++r) {
                const float v0 = fmaf(a0.x, qx[r], fmaf(a0.y, qy[r], fmaf(a0.z, qz[r], a0.w)));
                const float v1 = fmaf(a1.x, qx[r], fmaf(a1.y, qy[r], fmaf(a1.z, qz[r], a1.w)));
                const float v2 = fmaf(a2.x, qx[r], fmaf(a2.y, qy[r], fmaf(a2.z, qz[r], a2.w)));
                const float v3 = fmaf(a3.x, qx[r], fmaf(a3.y, qy[r], fmaf(a3.z, qz[r], a3.w)));
                m0[r][s0 + 0] = fminf(m0[r][s0 + 0], fminf(v0, v1));   // v_min3_f32
                m0[r][s0 + 1] = fminf(m0[r][s0 + 1], fminf(v2, v3));   // v_min3_f32
            }
        }
    }

    // per-lane exact sorted-4 of its 4 stream minima, stash to LDS
#pragma unroll
    for (int r = 0; r < RPW; ++r)
        sMerge[wave][r][lane] = sort4(m0[r]);
    __syncthreads();

    // waves 0,1 merge rows (own half + partner wave's half): eighth e (8 lanes)
    // owns row e; each lane folds 16 lists (8 own-wave + 8 partner) -> exact top-4.
    float tot = 0.0f;
    if (wave < 2) {
        const int e = lane >> 3;
        const int j = lane & 7;
        float4 G = make_float4(FLT_MAX, FLT_MAX, FLT_MAX, FLT_MAX);
#pragma unroll 1
        for (int t = 0; t < 8; ++t) {
            G = merge44(G, sMerge[wave][e][j + 8 * t]);
            G = merge44(G, sMerge[wave + 2][e][j + 8 * t]);
        }

        // qs[e] via static-index lane-bit mux (rule #20)
        const float qsa = (lane & 8) ? qs[1] : qs[0];
        const float qsb = (lane & 8) ? qs[3] : qs[2];
        const float qsc = (lane & 8) ? qs[5] : qs[4];
        const float qsd = (lane & 8) ? qs[7] : qs[6];
        const float qse = (lane & 16) ? qsb : qsa;
        const float qsf = (lane & 16) ? qsd : qsc;
        const float qsq = (lane & 32) ? qsf : qse;

        float G0 = G.x, G1 = G.y, G2 = G.z, G3 = G.w;
        float rsum = 0.0f;
#pragma unroll
        for (int k = 0; k < KNN; ++k) {
            float m = G0;
            m = fminf(m, __shfl_xor(m, 1, 64));
            m = fminf(m, __shfl_xor(m, 2, 64));
            m = fminf(m, __shfl_xor(m, 4, 64));
            rsum += fast_sqrt(fmaxf(qsq + m, 0.0f) + EPSV);
            const bool take = (G0 == m);
            G0 = take ? G1 : G0;
            G1 = take ? G2 : G1;
            G2 = take ? G3 : G2;
            G3 = take ? FLT_MAX : G3;
        }

        tot = rsum + __shfl_xor(rsum, 8, 64);
        tot += __shfl_xor(tot, 16, 64);
        tot += __shfl_xor(tot, 32, 64);
        if (lane == 0) sWaveSum[wave] = tot;
    }
    __syncthreads();
    if (tid == 0) outbuf[blk] = sWaveSum[0] + sWaveSum[1];
}

// ---------- fallback: R5's LDS-staged kernel (proven, unchanged) ----------
template <int ATOMIC>
__global__ __launch_bounds__(THREADS2)
__attribute__((amdgpu_waves_per_eu(2, 4)))
void knn_tv_lds(const float* __restrict__ pc, float* __restrict__ outbuf)
{
    __shared__ float sX[TILE2], sY[TILE2], sZ[TILE2], sS[TILE2];
    __shared__ float sWaveSum[WAVES2];

    const int tid   = threadIdx.x;
    const int lane  = tid & 63;
    const int wave  = tid >> 6;
    const int blk   = blockIdx.x;
    const int batch = blk / BPB2;
    const int row0  = (blk % BPB2) * RPB2 + wave * RPW2;

    const float* __restrict__ base = pc + (size_t)batch * (size_t)N * 3;

    float qx[RPW2], qy[RPW2], qz[RPW2], qs[RPW2];
#pragma unroll
    for (int r = 0; r < RPW2; ++r) {
        const int row = row0 + r;
        const float x = base[row * 3 + 0];
        const float y = base[row * 3 + 1];
        const float z = base[row * 3 + 2];
        qx[r] = rfl(-2.0f * x); qy[r] = rfl(-2.0f * y); qz[r] = rfl(-2.0f * z);
        qs[r] = rfl(fmaf(z, z, fmaf(y, y, x * x)));
    }

    float m0[RPW2][8];
#pragma unroll
    for (int r = 0; r < RPW2; ++r)
#pragma unroll
        for (int c = 0; c < 8; ++c) m0[r][c] = FLT_MAX;

    for (int tile = 0; tile < NTILES2; ++tile) {
        __syncthreads();
#pragma unroll
        for (int h = 0; h < 2; ++h) {
            const int p  = tid + h * THREADS2;
            const int gp = tile * TILE2 + p;
            const float x = base[gp * 3 + 0];
            const float y = base[gp * 3 + 1];
            const float z = base[gp * 3 + 2];
            sX[p] = x; sY[p] = y; sZ[p] = z;
            sS[p] = fmaf(z, z, fmaf(y, y, x * x));
        }
        __syncthreads();

#pragma unroll
        for (int grp = 0; grp < 4; ++grp) {
            const int o = grp * 256 + 4 * lane;
            const float4 CX = *(const float4*)&sX[o];
            const float4 CY = *(const float4*)&sY[o];
            const float4 CZ = *(const float4*)&sZ[o];
            const float4 CS = *(const float4*)&sS[o];
            const float cx[4] = {CX.x, CX.y, CX.z, CX.w};
            const float cy[4] = {CY.x, CY.y, CY.z, CY.w};
            const float cz[4] = {CZ.x, CZ.y, CZ.z, CZ.w};
            const float cs[4] = {CS.x, CS.y, CS.z, CS.w};
            const int jb = (grp & 1) * 4;
#pragma unroll
            for (int r = 0; r < RPW2; ++r)
#pragma unroll
                for (int i = 0; i < 4; ++i) {
                    const float v = fmaf(cx[i], qx[r], fmaf(cy[i], qy[r], fmaf(cz[i], qz[r], cs[i])));
                    m0[r][jb + i] = fminf(m0[r][jb + i], v);
                }
        }
    }

    float L[RPW2][4];
#pragma unroll
    for (int r = 0; r < RPW2; ++r) top4_of_8(m0[r], L[r]);

    const float wsum = merge_and_sum<RPW2>(L, qs);

    if (lane == 0) sWaveSum[wave] = wsum;
    __syncthreads();
    if (tid == 0) {
        float t = 0.0f;
#pragma unroll
        for (int w = 0; w < WAVES2; ++w) t += sWaveSum[w];
        if (ATOMIC) atomicAdd(outbuf, t * (1.0f / (float)(B * N)));
        else        outbuf[blk] = t;
    }
}

__global__ __launch_bounds__(256)
void knn_tv_reduce(const float* __restrict__ partial, float* __restrict__ out, int n)
{
    __shared__ float s[4];
    const int tid = threadIdx.x;
    float v = 0.0f;
    for (int i = tid; i < n; i += 256) v += partial[i];
#pragma unroll
    for (int off = 1; off < 64; off <<= 1) v += __shfl_xor(v, off, 64);
    if ((tid & 63) == 0) s[tid >> 6] = v;
    __syncthreads();
    if (tid == 0) {
        const float t = s[0] + s[1] + s[2] + s[3];
        out[0] = t * (1.0f / (float)(B * N));
    }
}

extern "C" void kernel_launch(void* const* d_in, const int* in_sizes, int n_in,
                              void* d_out, int out_size, void* d_ws, size_t ws_size,
                              hipStream_t stream)
{
    const float* pc  = (const float*)d_in[0];
    float*       out = (float*)d_out;

    if (ws_size >= PT4_BYTES + GRID * sizeof(float)) {
        float4* pt4     = (float4*)d_ws;
        float*  partial = (float*)((char*)d_ws + PT4_BYTES);
        knn_prep<<<(B * N + 255) / 256, 256, 0, stream>>>(pc, pt4);
        knn_tv_split<<<GRID, THREADS, 0, stream>>>(pt4, partial);
        knn_tv_reduce<<<1, 256, 0, stream>>>(partial, out, GRID);
    } else if (ws_size >= GRID2 * sizeof(float)) {
        float* partial = (float*)d_ws;
        knn_tv_lds<0><<<GRID2, THREADS2, 0, stream>>>(pc, partial);
        knn_tv_reduce<<<1, 256, 0, stream>>>(partial, out, GRID2);
    } else {
        hipMemsetAsync(d_out, 0, sizeof(float), stream);
        knn_tv_lds<1><<<GRID2, THREADS2, 0, stream>>>(pc, out);
    }
}